// Round 1
// baseline (116.989 us; speedup 1.0000x reference)
//
#include <hip/hip_runtime.h>
#include <stdint.h>

#define NN 1536
#define EE 49152
#define EMB 32
#define HEADS 3
#define SLOPE 0.2f
#define CAP 72             // per-row capacity; degree ~ Poisson(32), measured max ~60 (fixed seed); P(>=72) ~ 1e-10
#define EBLK (EE/256)      // 192 edge blocks, 256 edges each (1 thread/edge)
#define NBLK (NN/8)        // 192 node blocks

__device__ __forceinline__ float lrelu(float x){ return x >= 0.f ? x : SLOPE*x; }

// ---- runtime detection of bool-mask storage (int32 / uint8 / f32) ----
__device__ int detect_mask_layout(const unsigned char* p){
  const int* pi = (const int*)p;
  bool ok = true;
  for (int k=0;k<64 && ok;k++){ int v = pi[k]; ok = (v==0 || v==1); }
  if (ok) return 0;
  ok = true;
  for (int k=0;k<256 && ok;k++){ ok = (p[k] <= 1); }
  if (ok) return 1;
  return 2;
}
__device__ bool mask_at(const unsigned char* p, int layout, int i){
  if (layout==0) return ((const int*)p)[i] != 0;
  if (layout==1) return p[i] != 0;
  return ((const float*)p)[i] != 0.f;
}

// ---- K1: blocks [0,192): pure bucket insert (1 thread/edge, payload = dst + 4 raw attrs).
//          blocks [192, 384): node embeddings (unchanged). ----
__global__ __launch_bounds__(256) void k_prep(
    const float* __restrict__ node_f,
    const float* __restrict__ edge_attr, const float* __restrict__ edge_type,
    const float* __restrict__ W_veh, const float* __restrict__ W_ped,
    const float* __restrict__ W_att, const float* __restrict__ W_upd,
    const int* __restrict__ ei, const unsigned char* __restrict__ veh_mask,
    int* __restrict__ cnt, int* __restrict__ bucketD, float4* __restrict__ bucketF,
    float* __restrict__ tar, float* __restrict__ nbr, float* __restrict__ nb)
{
  const int t = threadIdx.x;
  const int b = blockIdx.x;

  if (b < EBLK){
    // -------- edge path: bucket insert only; embeddings recomputed in K2 --------
    const int e = b*256 + t;
    const int s = ei[e], d = ei[EE + e];
    const float2 ea = ((const float2*)edge_attr)[e];
    const float2 et = ((const float2*)edge_type)[e];
    const int idx = atomicAdd(&cnt[s], 1);
    if (idx < CAP){
      bucketD[(size_t)s*CAP + idx] = d;
      bucketF[(size_t)s*CAP + idx] = make_float4(ea.x, ea.y, et.x, et.y);
    }
    return;
  }

  // -------- node path: 8 nodes/block, 32 threads/node --------
  __shared__ float sWvehT[EMB*33], sWpedT[EMB*33], sWunT[EMB*33];
  __shared__ float sWt[HEADS*EMB], sWn[HEADS*EMB];
  __shared__ float sF[8*EMB], sEmb[8*EMB];
  __shared__ int layout_s;
  const int i0 = (b - EBLK)*8;
  if (t == 0) layout_s = detect_mask_layout(veh_mask);
  for (int idx=t; idx<EMB*EMB; idx+=256){
    const int mm = idx>>5, kk = idx&31;
    sWvehT[mm*33+kk] = W_veh[idx];
    sWpedT[mm*33+kk] = W_ped[idx];
    sWunT[mm*33+kk]  = W_upd[mm*64 + EMB + kk];   // Wu_n = W_upd[:,32:]
  }
  if (t < HEADS*EMB){
    const int h = t>>5, c = t&31;
    sWt[t] = W_att[h*128 + c];        // W_tar
    sWn[t] = W_att[h*128 + 96 + c];   // W_nbr
  }
  sF[t] = node_f[(size_t)i0*EMB + t];
  __syncthreads();

  const int li = t >> 5, m = t & 31;
  const int i = i0 + li;
  const bool veh = mask_at(veh_mask, layout_s, i);
  const float* WT = veh ? sWvehT : sWpedT;
  float a = 0.f;
  #pragma unroll
  for (int k=0;k<EMB;k++) a += sF[li*EMB+k] * WT[m*33+k];
  sEmb[li*EMB+m] = lrelu(a);
  __syncthreads();

  float bb = 0.f;
  #pragma unroll
  for (int k=0;k<EMB;k++) bb += sEmb[li*EMB+k] * sWunT[m*33+k];
  nb[(size_t)i*EMB + m] = bb;
  if (m < 3){
    float v = 0.f;
    #pragma unroll
    for (int k=0;k<EMB;k++) v += sEmb[li*EMB+k] * sWt[m*EMB+k];
    tar[i*4+m] = v;
  } else if (m < 6){
    const int h = m-3;
    float v = 0.f;
    #pragma unroll
    for (int k=0;k<EMB;k++) v += sEmb[li*EMB+k] * sWn[h*EMB+k];
    nbr[i*4+h] = v;
  }
}

// ---- K2: one block per src row; embeddings recomputed in LDS from raw payload ----
__global__ __launch_bounds__(256) void k_rows(
    const int* __restrict__ cnt, const int* __restrict__ bucketD,
    const float4* __restrict__ bucketF,
    const float* __restrict__ W_ea, const float* __restrict__ W_et,
    const float* __restrict__ W_att, const float* __restrict__ W_upd,
    const float* __restrict__ tar, const float* __restrict__ nbr,
    const float* __restrict__ nb, float* __restrict__ out)
{
  const int r = blockIdx.x;
  const int t = threadIdx.x;

  __shared__ int   ld[CAP], canon[CAP], slotidx[CAP], slotof[CAP], cdst[CAP];
  __shared__ float4 pay[CAP];
  __shared__ float sE[CAP*66];           // per-slot summed [emb_ea(32) | pad | emb_et(32) | pad]
  __shared__ float sWea[64], sWet[64], sWedge[HEADS*64], sWueT[EMB*33];
  __shared__ float pp[HEADS*CAP];
  __shared__ float partial[8*96];
  __shared__ float hden[HEADS];
  __shared__ int np_s;

  // stage small weights (always; cheap)
  if (t < 64){ sWea[t] = W_ea[t]; sWet[t] = W_et[t]; }
  if (t < HEADS*64) sWedge[t] = W_att[(t>>6)*128 + EMB + (t&63)];   // W_edge
  for (int idx=t; idx<EMB*EMB; idx+=256){
    const int o = idx>>5, k = idx&31;
    sWueT[o*33+k] = W_upd[o*64 + k];     // Wu_e = W_upd[:, :32]
  }
  if (t == 0) np_s = 0;

  const int K = min(cnt[r], CAP);

  if (K == 0){
    // all scores -10000 -> uniform attention over all nodes (lazy fallback; ~never taken)
    __shared__ float fb[EMB];
    if (t < EMB) fb[t] = 0.f;
    __syncthreads();
    for (int idx=t; idx<NN*EMB; idx+=256) atomicAdd(&fb[idx&31], lrelu(nb[idx]));
    __syncthreads();
    if (t < 96) out[(size_t)r*96 + t] = fb[t&31] * (1.0f/NN);
    return;
  }

  for (int i=t; i<K; i+=256){
    ld[i]  = bucketD[(size_t)r*CAP + i];
    pay[i] = bucketF[(size_t)r*CAP + i];
    canon[i] = i;
  }
  __syncthreads();

  // dedup: canon[i] = min j with ld[j]==ld[i] (all-parallel pair sweep)
  for (int p=t; p<K*K; p+=256){
    const int i = p / K, j = p - i*K;
    if (j < i && ld[i] == ld[j]) atomicMin(&canon[i], j);
  }
  __syncthreads();
  for (int i=t; i<K; i+=256){
    if (canon[i] == i){
      const int s2 = atomicAdd(&np_s, 1);
      slotidx[i] = s2;
      cdst[s2]   = ld[i];
    }
  }
  __syncthreads();
  const int Kc = np_s;
  const bool nodup = (Kc == K);     // block-uniform

  for (int i=t; i<K; i+=256) slotof[i] = slotidx[canon[i]];
  if (!nodup){
    for (int idx=t; idx<Kc*66; idx+=256) sE[idx] = 0.f;
  }
  __syncthreads();

  // per-entry 64-dim edge embedding -> per-slot sum (linear downstream, so summing embs == summing eau/se)
  for (int idx=t; idx<K*EMB; idx+=256){
    const int q = idx>>5, m = idx&31;
    const float4 p4 = pay[q];
    const float ea_ = lrelu(p4.x*sWea[2*m] + p4.y*sWea[2*m+1]);
    const float et_ = lrelu(p4.z*sWet[2*m] + p4.w*sWet[2*m+1]);
    const int sl = slotof[q];
    if (nodup){
      sE[sl*66 + m]      = ea_;
      sE[sl*66 + 33 + m] = et_;
    } else {
      atomicAdd(&sE[sl*66 + m],      ea_);
      atomicAdd(&sE[sl*66 + 33 + m], et_);
    }
  }
  __syncthreads();

  // softmax: head h = wave h; lane q; shfl reductions; se computed from sE on the fly
  if (t < 192){
    const int h = t >> 6, lane = t & 63;
    const float th = tar[r*4+h];
    float mx = -1e30f;
    for (int q0=0; q0<Kc; q0+=64){
      const int q = q0 + lane;
      if (q < Kc){
        float sev = 0.f;
        #pragma unroll
        for (int k=0;k<EMB;k++)
          sev += sWedge[h*64+k]*sE[q*66+k] + sWedge[h*64+EMB+k]*sE[q*66+33+k];
        const float s = lrelu(th + sev + nbr[cdst[q]*4+h]);
        pp[h*CAP+q] = s;
        mx = fmaxf(mx, s);
      }
    }
    #pragma unroll
    for (int d=32; d; d>>=1) mx = fmaxf(mx, __shfl_xor(mx, d, 64));
    float den = 0.f;
    for (int q0=0; q0<Kc; q0+=64){
      const int q = q0 + lane;
      if (q < Kc){
        const float p = __expf(pp[h*CAP+q] - mx);
        pp[h*CAP+q] = p;
        den += p;
      }
    }
    #pragma unroll
    for (int d=32; d; d>>=1) den += __shfl_xor(den, d, 64);
    if (lane == 0) hden[h] = den;
  }
  __syncthreads();

  // output: 8 q-groups x 32 o-lanes; eau recomputed from sE (broadcast row) x sWueT
  {
    const int g = t >> 5, o = t & 31;
    float a0=0.f, a1=0.f, a2=0.f;
    for (int q=g; q<Kc; q+=8){
      float ev = 0.f;
      #pragma unroll
      for (int k=0;k<EMB;k++) ev += sWueT[o*33+k] * sE[q*66+k];
      const float u = lrelu(ev + nb[(size_t)cdst[q]*EMB + o]);
      a0 += pp[0*CAP+q]*u;
      a1 += pp[1*CAP+q]*u;
      a2 += pp[2*CAP+q]*u;
    }
    partial[g*96 +      o] = a0;
    partial[g*96 + 32 + o] = a1;
    partial[g*96 + 64 + o] = a2;
  }
  __syncthreads();
  if (t < 96){
    float s = 0.f;
    #pragma unroll
    for (int g=0; g<8; g++) s += partial[g*96 + t];
    out[(size_t)r*96 + t] = s / hden[t>>5];
  }
}

extern "C" void kernel_launch(void* const* d_in, const int* in_sizes, int n_in,
                              void* d_out, int out_size, void* d_ws, size_t ws_size,
                              hipStream_t stream)
{
  (void)in_sizes; (void)n_in; (void)out_size; (void)ws_size;
  const float* node_f    = (const float*)d_in[0];
  const float* edge_attr = (const float*)d_in[1];
  const float* edge_type = (const float*)d_in[2];
  const float* W_veh     = (const float*)d_in[3];
  const float* W_ped     = (const float*)d_in[4];
  const float* W_ea      = (const float*)d_in[5];
  const float* W_et      = (const float*)d_in[6];
  const float* W_att     = (const float*)d_in[7];
  const float* W_upd     = (const float*)d_in[8];
  const int*   ei        = (const int*)d_in[9];
  const unsigned char* veh_mask = (const unsigned char*)d_in[10];
  float* out = (float*)d_out;

  char* ws = (char*)d_ws;
  const size_t oCnt  = 0;                            // NN ints (zeroed: 6 KB)
  const size_t oBktF = oCnt  + (size_t)NN*4;         // NN*CAP float4 (16B-aligned: 6144 % 16 == 0)
  const size_t oBktD = oBktF + (size_t)NN*CAP*16;    // NN*CAP ints
  const size_t oTar  = oBktD + (size_t)NN*CAP*4;     // NN*4 floats
  const size_t oNbr  = oTar  + (size_t)NN*4*4;       // NN*4 floats
  const size_t oNb   = oNbr  + (size_t)NN*4*4;       // NN*32 floats

  int*    cnt     = (int*)   (ws + oCnt);
  float4* bucketF = (float4*)(ws + oBktF);
  int*    bucketD = (int*)   (ws + oBktD);
  float*  tar     = (float*) (ws + oTar);
  float*  nbr     = (float*) (ws + oNbr);
  float*  nb      = (float*) (ws + oNb);

  hipMemsetAsync(ws + oCnt, 0, (size_t)NN*4, stream);   // cnt = 0 (6 KB only)

  k_prep<<<EBLK + NBLK, 256, 0, stream>>>(node_f, edge_attr, edge_type,
                                          W_veh, W_ped, W_att, W_upd,
                                          ei, veh_mask, cnt, bucketD, bucketF,
                                          tar, nbr, nb);
  k_rows<<<NN, 256, 0, stream>>>(cnt, bucketD, bucketF, W_ea, W_et, W_att, W_upd,
                                 tar, nbr, nb, out);
}